// Round 4
// baseline (170.803 us; speedup 1.0000x reference)
//
#include <hip/hip_runtime.h>
#include <hip/hip_bf16.h>

// Problem constants (QuadraticAttention): B=2, T=2048, D_MODEL=1024, H=16, d=64
#define TSEQ   2048
#define DM     1024
#define NHEAD  16
#define DH     64
#define BATCH  2
#define MR     (BATCH * TSEQ)   // 4096 rows
#define CH     64               // attention chunk length
#define NC     (TSEQ / CH)      // 32 chunks per sequence
#define QKVLD  (3 * DM)         // 3072 fused N
#define LP     72               // padded LDS row stride (bf16): 2-way max on b128 reads

typedef __attribute__((ext_vector_type(8))) short bf16x8;
typedef __attribute__((ext_vector_type(4))) float f32x4;

__device__ __forceinline__ short f2bf(float x) {
  __hip_bfloat16 h = __float2bfloat16(x);
  return *reinterpret_cast<short*>(&h);
}

__device__ __forceinline__ void stage16(const void* g, void* l) {
  __builtin_amdgcn_global_load_lds(
      (const __attribute__((address_space(1))) void*)g,
      (__attribute__((address_space(3))) void*)l, 16, 0, 0);
}

// ---------------------------------------------------------------------------
// Fused QKV GEMM: [4096,1024] @ [1024,3072]. m97 structure, 128x128, BK=32.
// Epilogue by N-region (block-uniform):
//   Q (cols 0-1023):    qb natural [MR][DM] bf16
//   K (1024-2047):      kb natural AND kT tiles [b][h][c][i][s] (packed 8B)
//   V (2048-3071):      vT tiles [b][h][c][j][s] only (packed 8B)
// ---------------------------------------------------------------------------
__global__ __launch_bounds__(256) void gemm_qkv(const short* __restrict__ A,
                                                const short* __restrict__ Bt,
                                                short* __restrict__ qb,
                                                short* __restrict__ kb,
                                                short* __restrict__ kT,
                                                short* __restrict__ vT) {
  const int K = DM;
  __shared__ short As[128][32];
  __shared__ short Bs[128][32];
  const int tid = threadIdx.x;
  const int lane = tid & 63, wid = tid >> 6;
  const int wave_m = wid >> 1, wave_n = wid & 1;
  const int row0 = blockIdx.y * 128, col0 = blockIdx.x * 128;

  const int sr = tid >> 2, sk = (tid & 3) * 8;
  const short* Ag0 = A + (size_t)(row0 + sr) * K + sk;
  const short* Bg0 = Bt + (size_t)(col0 + sr) * K + sk;
  short* AsL = &As[0][0] + tid * 8;
  short* BsL = &Bs[0][0] + tid * 8;

  f32x4 acc[4][4];
#pragma unroll
  for (int i = 0; i < 4; ++i)
#pragma unroll
    for (int j = 0; j < 4; ++j) acc[i][j] = (f32x4){0.f, 0.f, 0.f, 0.f};

  const int fm = wave_m * 64 + (lane & 15);
  const int fn = wave_n * 64 + (lane & 15);
  const int fk = (lane >> 4) * 8;

  for (int k0 = 0; k0 < K; k0 += 32) {
    stage16(Ag0 + k0, AsL);
    stage16(Ag0 + (size_t)64 * K + k0, AsL + 2048);
    stage16(Bg0 + k0, BsL);
    stage16(Bg0 + (size_t)64 * K + k0, BsL + 2048);
    __syncthreads();
    bf16x8 af[4], bf[4];
#pragma unroll
    for (int t = 0; t < 4; ++t) {
      af[t] = *(const bf16x8*)&As[fm + t * 16][fk];
      bf[t] = *(const bf16x8*)&Bs[fn + t * 16][fk];
    }
#pragma unroll
    for (int im = 0; im < 4; ++im)
#pragma unroll
      for (int jn = 0; jn < 4; ++jn)
        acc[im][jn] = __builtin_amdgcn_mfma_f32_16x16x32_bf16(af[im], bf[jn], acc[im][jn], 0, 0, 0);
    __syncthreads();
  }

  const int crow = (lane >> 4) * 4, ccol = lane & 15;
  const int region = col0 >> 10;   // 0=Q, 1=K, 2=V (block-uniform)

  if (region <= 1) {
    short* Cb = (region == 0) ? qb : kb;
#pragma unroll
    for (int im = 0; im < 4; ++im)
#pragma unroll
      for (int jn = 0; jn < 4; ++jn) {
        const int gr = row0 + wave_m * 64 + im * 16 + crow;
        const int gc = (col0 & 1023) + wave_n * 64 + jn * 16 + ccol;
        short* Cp = Cb + (size_t)gr * DM + gc;
#pragma unroll
        for (int r = 0; r < 4; ++r) Cp[(size_t)r * DM] = f2bf(acc[im][jn][r]);
      }
  }
  if (region >= 1) {
    short* Tt = (region == 1) ? kT : vT;
    const int gr0 = row0 + wave_m * 64;         // chunk-aligned (64 rows)
    const int b = gr0 >> 11;                    // / TSEQ
    const int c = (gr0 & 2047) >> 6;
#pragma unroll
    for (int im = 0; im < 4; ++im)
#pragma unroll
      for (int jn = 0; jn < 4; ++jn) {
        const int gcol = (col0 & 1023) + wave_n * 64 + jn * 16 + ccol;
        const int h = gcol >> 6, i = gcol & 63;
        const int s0 = im * 16 + crow;          // 4 consecutive s per lane
        size_t idx = ((((size_t)(b * NHEAD + h) * NC + c) * DH + i) * DH + s0);
        union { short h4[4]; uint2 u; } pk;
#pragma unroll
        for (int r = 0; r < 4; ++r) pk.h4[r] = f2bf(acc[im][jn][r]);
        *(uint2*)(Tt + idx) = pk.u;
      }
  }
}

// ---------------------------------------------------------------------------
// Output projection GEMM: [4096,1024] @ [1024,1024] -> fp32 out.
// ---------------------------------------------------------------------------
__global__ __launch_bounds__(256) void gemm_out(const short* __restrict__ A,
                                                const short* __restrict__ Bt,
                                                float* __restrict__ C) {
  const int K = DM, N = DM;
  __shared__ short As[128][32];
  __shared__ short Bs[128][32];
  const int tid = threadIdx.x;
  const int lane = tid & 63, wid = tid >> 6;
  const int wave_m = wid >> 1, wave_n = wid & 1;
  const int row0 = blockIdx.y * 128, col0 = blockIdx.x * 128;

  const int sr = tid >> 2, sk = (tid & 3) * 8;
  const short* Ag0 = A + (size_t)(row0 + sr) * K + sk;
  const short* Bg0 = Bt + (size_t)(col0 + sr) * K + sk;
  short* AsL = &As[0][0] + tid * 8;
  short* BsL = &Bs[0][0] + tid * 8;

  f32x4 acc[4][4];
#pragma unroll
  for (int i = 0; i < 4; ++i)
#pragma unroll
    for (int j = 0; j < 4; ++j) acc[i][j] = (f32x4){0.f, 0.f, 0.f, 0.f};

  const int fm = wave_m * 64 + (lane & 15);
  const int fn = wave_n * 64 + (lane & 15);
  const int fk = (lane >> 4) * 8;

  for (int k0 = 0; k0 < K; k0 += 32) {
    stage16(Ag0 + k0, AsL);
    stage16(Ag0 + (size_t)64 * K + k0, AsL + 2048);
    stage16(Bg0 + k0, BsL);
    stage16(Bg0 + (size_t)64 * K + k0, BsL + 2048);
    __syncthreads();
    bf16x8 af[4], bf[4];
#pragma unroll
    for (int t = 0; t < 4; ++t) {
      af[t] = *(const bf16x8*)&As[fm + t * 16][fk];
      bf[t] = *(const bf16x8*)&Bs[fn + t * 16][fk];
    }
#pragma unroll
    for (int im = 0; im < 4; ++im)
#pragma unroll
      for (int jn = 0; jn < 4; ++jn)
        acc[im][jn] = __builtin_amdgcn_mfma_f32_16x16x32_bf16(af[im], bf[jn], acc[im][jn], 0, 0, 0);
    __syncthreads();
  }

  const int crow = (lane >> 4) * 4, ccol = lane & 15;
#pragma unroll
  for (int im = 0; im < 4; ++im)
#pragma unroll
    for (int jn = 0; jn < 4; ++jn) {
      float* Cp = C + (size_t)(row0 + wave_m * 64 + im * 16 + crow) * N
                    + col0 + wave_n * 64 + jn * 16 + ccol;
#pragma unroll
      for (int r = 0; r < 4; ++r) Cp[(size_t)r * N] = acc[im][jn][r];
    }
}

// ---------------------------------------------------------------------------
// prep: z<4 -> transpose W_z (fp32 [K][N] -> bf16 [N][K]); z==4 -> x fp32->bf16.
// ---------------------------------------------------------------------------
__global__ __launch_bounds__(256) void prep(const float* __restrict__ x,
                                            const float* __restrict__ W0,
                                            const float* __restrict__ W1,
                                            const float* __restrict__ W2,
                                            const float* __restrict__ W3,
                                            __hip_bfloat16* __restrict__ xb,
                                            __hip_bfloat16* __restrict__ Wt) {
  const int tid = threadIdx.x;
  if (blockIdx.z == 4) {
    // x conversion: 256 blocks x 16384 floats each
    const int bid = blockIdx.y * 16 + blockIdx.x;
    const float* src = x + (size_t)bid * 16384;
    __hip_bfloat16* dst = xb + (size_t)bid * 16384;
#pragma unroll
    for (int it = 0; it < 16; ++it) {
      int i = it * 1024 + tid * 4;
      float4 v = *(const float4*)(src + i);
      union { __hip_bfloat16 h[4]; uint2 u; } pk;
      pk.h[0] = __float2bfloat16(v.x); pk.h[1] = __float2bfloat16(v.y);
      pk.h[2] = __float2bfloat16(v.z); pk.h[3] = __float2bfloat16(v.w);
      *(uint2*)(dst + i) = pk.u;
    }
    return;
  }
  const float* W = blockIdx.z == 0 ? W0 : blockIdx.z == 1 ? W1 : blockIdx.z == 2 ? W2 : W3;
  __hip_bfloat16* out = Wt + (size_t)blockIdx.z * DM * DM;
  __shared__ float tile[64][65];
  const int kt = blockIdx.y * 64, nt = blockIdx.x * 64;
  const int lr = tid >> 6, lc = tid & 63;
#pragma unroll
  for (int i = 0; i < 16; ++i) {
    int k = i * 4 + lr;
    tile[k][lc] = W[(size_t)(kt + k) * DM + nt + lc];
  }
  __syncthreads();
  const int nl = tid >> 4, k4 = (tid & 15) * 4;
#pragma unroll
  for (int i = 0; i < 4; ++i) {
    int n = i * 16 + nl;
    union { __hip_bfloat16 h[4]; uint2 u; } pk;
#pragma unroll
    for (int xx = 0; xx < 4; ++xx) pk.h[xx] = __float2bfloat16(tile[k4 + xx][n]);
    *(uint2*)(out + (size_t)(nt + n) * DM + kt + k4) = pk.u;
  }
}

// ---------------------------------------------------------------------------
// Phase A (LDS-free MFMA): Mc[j][i] = sum_s V^T[j][s] * K^T[i][s] from kT/vT
// tiles. One block per (c,h,b); wave w does rows 16w..16w+15.
// ---------------------------------------------------------------------------
__global__ __launch_bounds__(256) void chunk_kv(const short* __restrict__ kT,
                                                const short* __restrict__ vT,
                                                float* __restrict__ Mc) {
  const int c = blockIdx.x, h = blockIdx.y, b = blockIdx.z;
  const size_t tile = ((size_t)(b * NHEAD + h) * NC + c) * (DH * DH);
  const int tid = threadIdx.x, lane = tid & 63, w = tid >> 6;
  const int m = lane & 15, q = lane >> 4;
  const short* vt = vT + tile;
  const short* kt = kT + tile;
  bf16x8 a0 = *(const bf16x8*)(vt + (16 * w + m) * DH + q * 8);
  bf16x8 a1 = *(const bf16x8*)(vt + (16 * w + m) * DH + q * 8 + 32);
  f32x4 acc[4];
#pragma unroll
  for (int ct = 0; ct < 4; ++ct) acc[ct] = (f32x4){0.f, 0.f, 0.f, 0.f};
#pragma unroll
  for (int ct = 0; ct < 4; ++ct) {
    bf16x8 b0 = *(const bf16x8*)(kt + (ct * 16 + m) * DH + q * 8);
    bf16x8 b1 = *(const bf16x8*)(kt + (ct * 16 + m) * DH + q * 8 + 32);
    acc[ct] = __builtin_amdgcn_mfma_f32_16x16x32_bf16(a0, b0, acc[ct], 0, 0, 0);
    acc[ct] = __builtin_amdgcn_mfma_f32_16x16x32_bf16(a1, b1, acc[ct], 0, 0, 0);
  }
  float* out = Mc + tile;
#pragma unroll
  for (int ct = 0; ct < 4; ++ct)
#pragma unroll
    for (int rr = 0; rr < 4; ++rr)
      out[(size_t)(16 * w + q * 4 + rr) * DH + ct * 16 + m] = acc[ct][rr];
}

// ---------------------------------------------------------------------------
// Phase B: exclusive prefix over 32 chunks (fp32 in, bf16 out). [j][i] layout.
// ---------------------------------------------------------------------------
__global__ __launch_bounds__(256) void scan_states(const float* __restrict__ Mc,
                                                   __hip_bfloat16* __restrict__ Spre) {
  const int bh = blockIdx.y;
  const size_t off = (size_t)bh * NC * (DH * DH) + blockIdx.x * 256 + threadIdx.x;
  const float* src = Mc + off;
  __hip_bfloat16* dst = Spre + off;
  float run = 0.f;
  for (int c = 0; c < NC; ++c) {
    dst[(size_t)c * (DH * DH)] = __float2bfloat16(run);
    run += src[(size_t)c * (DH * DH)];
  }
}

// ---------------------------------------------------------------------------
// Phase C (MFMA, transposed orientation): per (b,h,chunk),
//   O^T[j][t] = sum_i St[j][i] Q[t][i]  +  sum_s V^T[j][s] P[t][s]
// A-frags come straight from global tiles (Spre [j][i], vT [j][s]);
// B-frags from LDS (Qs natural; Ks natural -> reused for masked P[t][s]).
// LDS = 18 KB. Packed 8B output stores.
// ---------------------------------------------------------------------------
__global__ __launch_bounds__(256) void intra_attn(const short* __restrict__ qb,
                                                  const short* __restrict__ kb,
                                                  const short* __restrict__ vT,
                                                  const short* __restrict__ Spre,
                                                  short* __restrict__ O_) {
  const int c = blockIdx.x, h = blockIdx.y, b = blockIdx.z;
  __shared__ short Qs[CH][LP];
  __shared__ short Ks[CH][LP];   // K -> then P
  const int tid = threadIdx.x, lane = tid & 63, w = tid >> 6;
  const int m = lane & 15, q = lane >> 4;
  const int r = tid >> 2, q16 = (tid & 3) * 16;
  const size_t tile = ((size_t)(b * NHEAD + h) * NC + c) * (DH * DH);
  const size_t grow = ((size_t)(b * TSEQ + c * CH + r)) * DM + h * DH;
  *(bf16x8*)&Qs[r][q16]     = *(const bf16x8*)(qb + grow + q16);
  *(bf16x8*)&Qs[r][q16 + 8] = *(const bf16x8*)(qb + grow + q16 + 8);
  *(bf16x8*)&Ks[r][q16]     = *(const bf16x8*)(kb + grow + q16);
  *(bf16x8*)&Ks[r][q16 + 8] = *(const bf16x8*)(kb + grow + q16 + 8);
  const short* vt = vT + tile;
  const short* st = Spre + tile;
  // A-frags from global (L2-hot tiles)
  bf16x8 av0 = *(const bf16x8*)(vt + (16 * w + m) * DH + q * 8);
  bf16x8 av1 = *(const bf16x8*)(vt + (16 * w + m) * DH + q * 8 + 32);
  bf16x8 as0 = *(const bf16x8*)(st + (16 * w + m) * DH + q * 8);
  bf16x8 as1 = *(const bf16x8*)(st + (16 * w + m) * DH + q * 8 + 32);
  __syncthreads();

  // A-frag for scores: Q strip (this wave's t rows)
  bf16x8 aq0 = *(const bf16x8*)&Qs[16 * w + m][q * 8];
  bf16x8 aq1 = *(const bf16x8*)&Qs[16 * w + m][q * 8 + 32];

  f32x4 acc[4], pacc[4];
#pragma unroll
  for (int ct = 0; ct < 4; ++ct) {
    acc[ct] = (f32x4){0.f, 0.f, 0.f, 0.f};
    pacc[ct] = (f32x4){0.f, 0.f, 0.f, 0.f};
  }
#pragma unroll
  for (int ct = 0; ct < 4; ++ct) {
    // G1': acc[j][t] += St[j][i] * Q[t][i]   (B from Qs rows ct*16+m)
    bf16x8 bq0 = *(const bf16x8*)&Qs[ct * 16 + m][q * 8];
    bf16x8 bq1 = *(const bf16x8*)&Qs[ct * 16 + m][q * 8 + 32];
    acc[ct] = __builtin_amdgcn_mfma_f32_16x16x32_bf16(as0, bq0, acc[ct], 0, 0, 0);
    acc[ct] = __builtin_amdgcn_mfma_f32_16x16x32_bf16(as1, bq1, acc[ct], 0, 0, 0);
    // G2: pacc[t][s] += Q[t][i] * K[s][i]    (B from Ks rows ct*16+m)
    bf16x8 bk0 = *(const bf16x8*)&Ks[ct * 16 + m][q * 8];
    bf16x8 bk1 = *(const bf16x8*)&Ks[ct * 16 + m][q * 8 + 32];
    pacc[ct] = __builtin_amdgcn_mfma_f32_16x16x32_bf16(aq0, bk0, pacc[ct], 0, 0, 0);
    pacc[ct] = __builtin_amdgcn_mfma_f32_16x16x32_bf16(aq1, bk1, pacc[ct], 0, 0, 0);
  }
  __syncthreads();   // all waves done reading Ks (K)
  // strict causal mask (keep s < t); write P[t][s] into Ks storage
#pragma unroll
  for (int ct = 0; ct < 4; ++ct) {
    const int s = ct * 16 + m;
#pragma unroll
    for (int rr = 0; rr < 4; ++rr) {
      const int t = 16 * w + q * 4 + rr;
      Ks[t][s] = f2bf((s < t) ? pacc[ct][rr] : 0.f);
    }
  }
  __syncthreads();
  // G3': acc[j][t] += V^T[j][s] * P[t][s]    (B from Ks(P) rows ct*16+m)
#pragma unroll
  for (int ct = 0; ct < 4; ++ct) {
    bf16x8 bp0 = *(const bf16x8*)&Ks[ct * 16 + m][q * 8];
    bf16x8 bp1 = *(const bf16x8*)&Ks[ct * 16 + m][q * 8 + 32];
    acc[ct] = __builtin_amdgcn_mfma_f32_16x16x32_bf16(av0, bp0, acc[ct], 0, 0, 0);
    acc[ct] = __builtin_amdgcn_mfma_f32_16x16x32_bf16(av1, bp1, acc[ct], 0, 0, 0);
  }
  // store O[t][h*64+j]: lane holds 4 consecutive j for fixed t -> 8B pack
#pragma unroll
  for (int ct = 0; ct < 4; ++ct) {
    const int t = ct * 16 + m, j0 = 16 * w + q * 4;
    union { short h4[4]; uint2 u; } pk;
#pragma unroll
    for (int rr = 0; rr < 4; ++rr) pk.h4[rr] = f2bf(acc[ct][rr]);
    *(uint2*)(O_ + ((size_t)(b * TSEQ + c * CH + t)) * DM + h * DH + j0) = pk.u;
  }
}

// ---------------------------------------------------------------------------
extern "C" void kernel_launch(void* const* d_in, const int* in_sizes, int n_in,
                              void* d_out, int out_size, void* d_ws, size_t ws_size,
                              hipStream_t stream) {
  const float* x  = (const float*)d_in[0];
  const float* Wq = (const float*)d_in[1];
  const float* Wk = (const float*)d_in[2];
  const float* Wv = (const float*)d_in[3];
  const float* Wo = (const float*)d_in[4];
  float* out = (float*)d_out;

  char* ws = (char*)d_ws;
  short* xb    = (short*)ws;  ws += (size_t)MR * DM * 2;               // 8 MB
  short* WtAll = (short*)ws;  ws += (size_t)4 * DM * DM * 2;           // 8 MB
  short* qb    = (short*)ws;  ws += (size_t)MR * DM * 2;               // 8 MB
  short* kb    = (short*)ws;  ws += (size_t)MR * DM * 2;               // 8 MB
  short* kT    = (short*)ws;  ws += (size_t)MR * DM * 2;               // 8 MB
  short* vT    = (short*)ws;  ws += (size_t)MR * DM * 2;               // 8 MB
  float* Mc    = (float*)ws;  ws += (size_t)MR * DM * 4;               // 16 MB
  short* Spre  = (short*)ws;  ws += (size_t)MR * DM * 2;               // 8 MB
  short* aob   = (short*)ws;  ws += (size_t)MR * DM * 2;               // 8 MB

  prep<<<dim3(16, 16, 5), 256, 0, stream>>>(x, Wq, Wk, Wv, Wo,
                                            (__hip_bfloat16*)xb, (__hip_bfloat16*)WtAll);

  gemm_qkv<<<dim3(QKVLD / 128, MR / 128), 256, 0, stream>>>(xb, WtAll, qb, kb, kT, vT);

  chunk_kv<<<dim3(NC, NHEAD, BATCH), 256, 0, stream>>>(kT, vT, Mc);
  scan_states<<<dim3(DH * DH / 256, BATCH * NHEAD), 256, 0, stream>>>(
      Mc, (__hip_bfloat16*)Spre);
  intra_attn<<<dim3(NC, NHEAD, BATCH), 256, 0, stream>>>(qb, kb, vT, Spre, aob);

  gemm_out<<<dim3(DM / 128, MR / 128), 256, 0, stream>>>(
      aob, WtAll + (size_t)3 * DM * DM, out);
}